// Round 1
// baseline (143.398 us; speedup 1.0000x reference)
//
#include <hip/hip_runtime.h>

#define N_PTS   4096
#define N_BATCH 16
#define BLOCK   256

__global__ void zero_out_kernel(float* out) { out[0] = 0.0f; }

// Pack (x, y, z) -> (x, y, z, x^2+y^2+z^2) for both point sets.
__global__ void pack_kernel(const float* __restrict__ tpl,
                            const float* __restrict__ src,
                            float4* __restrict__ ptpl,
                            float4* __restrict__ psrc) {
    int idx = blockIdx.x * blockDim.x + threadIdx.x;  // 0 .. 16*4096-1
    float x = tpl[idx * 3 + 0];
    float y = tpl[idx * 3 + 1];
    float z = tpl[idx * 3 + 2];
    ptpl[idx] = make_float4(x, y, z, fmaf(x, x, fmaf(y, y, z * z)));
    x = src[idx * 3 + 0];
    y = src[idx * 3 + 1];
    z = src[idx * 3 + 2];
    psrc[idx] = make_float4(x, y, z, fmaf(x, x, fmaf(y, y, z * z)));
}

// dir 0: for each SOURCE point, min over template points (dist1)
// dir 1: for each TEMPLATE point, min over source points (dist2)
// Per pair: min_i(|a_i|^2 - 2 a_i.b_j), own |b_j|^2 folded in after the loop.
__global__ __launch_bounds__(BLOCK, 2) void chamfer_main(
    const float4* __restrict__ ptpl,
    const float4* __restrict__ psrc,
    float* __restrict__ out) {
    __shared__ float4 buf[N_PTS];  // 64 KB: full opposite set for this batch

    const int batch = blockIdx.y;
    const int dir   = blockIdx.z;
    const float4* pts = (dir == 0) ? psrc : ptpl;
    const float4* oth = (dir == 0) ? ptpl : psrc;
    const int base = batch * N_PTS;

    // Stage opposite set into LDS (coalesced float4 loads).
    #pragma unroll
    for (int r = 0; r < N_PTS / BLOCK; ++r)
        buf[threadIdx.x + BLOCK * r] = oth[base + threadIdx.x + BLOCK * r];
    __syncthreads();

    const float4 p = pts[base + blockIdx.x * BLOCK + threadIdx.x];
    const float m2x = -2.0f * p.x;
    const float m2y = -2.0f * p.y;
    const float m2z = -2.0f * p.z;

    float d0 = 1e30f, d1 = 1e30f, d2 = 1e30f, d3 = 1e30f;
    #pragma unroll 4
    for (int k = 0; k < N_PTS; k += 4) {
        // Wave-uniform index -> LDS broadcast reads (no bank conflicts).
        float4 o0 = buf[k + 0];
        float4 o1 = buf[k + 1];
        float4 o2 = buf[k + 2];
        float4 o3 = buf[k + 3];
        float t0 = fmaf(m2z, o0.z, fmaf(m2y, o0.y, fmaf(m2x, o0.x, o0.w)));
        float t1 = fmaf(m2z, o1.z, fmaf(m2y, o1.y, fmaf(m2x, o1.x, o1.w)));
        float t2 = fmaf(m2z, o2.z, fmaf(m2y, o2.y, fmaf(m2x, o2.x, o2.w)));
        float t3 = fmaf(m2z, o3.z, fmaf(m2y, o3.y, fmaf(m2x, o3.x, o3.w)));
        d0 = fminf(d0, t0);
        d1 = fminf(d1, t1);
        d2 = fminf(d2, t2);
        d3 = fminf(d3, t3);
    }

    float dmin = fminf(fminf(d0, d1), fminf(d2, d3)) + p.w;
    dmin = fmaxf(dmin, 0.0f);  // clamp cancellation negatives (matches jnp.maximum)
    float val = sqrtf(dmin) * (1.0f / (2.0f * N_BATCH * N_PTS));

    // Wave64 shuffle reduction, then one atomic per wave.
    #pragma unroll
    for (int off = 32; off > 0; off >>= 1)
        val += __shfl_down(val, off);
    if ((threadIdx.x & 63) == 0)
        atomicAdd(out, val);
}

extern "C" void kernel_launch(void* const* d_in, const int* in_sizes, int n_in,
                              void* d_out, int out_size, void* d_ws, size_t ws_size,
                              hipStream_t stream) {
    const float* tpl = (const float*)d_in[0];
    const float* src = (const float*)d_in[1];
    float* out = (float*)d_out;

    float4* ptpl = (float4*)d_ws;                     // 16*4096 float4 = 1 MB
    float4* psrc = ptpl + (size_t)N_BATCH * N_PTS;    // another 1 MB

    hipLaunchKernelGGL(zero_out_kernel, dim3(1), dim3(1), 0, stream, out);
    hipLaunchKernelGGL(pack_kernel, dim3((N_BATCH * N_PTS) / BLOCK), dim3(BLOCK),
                       0, stream, tpl, src, ptpl, psrc);
    dim3 grid(N_PTS / BLOCK, N_BATCH, 2);
    hipLaunchKernelGGL(chamfer_main, grid, dim3(BLOCK), 0, stream, ptpl, psrc, out);
}

// Round 2
// 126.818 us; speedup vs baseline: 1.1307x; 1.1307x over previous
//
#include <hip/hip_runtime.h>

#define N_PTS   4096
#define N_BATCH 16
#define BLOCK   256
#define Q       8                 // query points per thread (register tile)
#define QTILE   (BLOCK * Q)       // 2048
#define KTILE   512               // opposite points staged in LDS (8 KB)
#define KSPLIT  (N_PTS / KTILE)   // 8
#define QT_PER  (N_PTS / QTILE)   // 2
#define INV_CNT (1.0f / (2.0f * N_BATCH * N_PTS))

// Partial mins: block handles QTILE queries x KTILE opposite points.
// Each LDS read is reused Q=8x in registers -> VALU-bound inner loop.
__global__ __launch_bounds__(BLOCK) void chamfer_partial(
    const float* __restrict__ tpl, const float* __restrict__ src,
    float* __restrict__ partial, float* __restrict__ out) {
    __shared__ float4 buf[KTILE];

    const int qt    = blockIdx.x & (QT_PER - 1);
    const int ks    = blockIdx.x >> 1;            // QT_PER == 2
    const int batch = blockIdx.y;
    const int dir   = blockIdx.z;
    const float* pts = (dir == 0) ? src : tpl;    // dist1: per source point
    const float* oth = (dir == 0) ? tpl : src;
    const int base = batch * N_PTS;

    if (blockIdx.x == 0 && batch == 0 && dir == 0 && threadIdx.x == 0)
        out[0] = 0.0f;   // combine kernel's atomics run strictly after (stream order)

    // Stage + pack opposite tile: (x,y,z) -> (x,y,z,|o|^2)
    #pragma unroll
    for (int r = 0; r < KTILE / BLOCK; ++r) {
        int i = threadIdx.x + BLOCK * r;
        const float* o = oth + 3 * (base + ks * KTILE + i);
        float x = o[0], y = o[1], z = o[2];
        buf[i] = make_float4(x, y, z, fmaf(x, x, fmaf(y, y, z * z)));
    }

    // Load Q query points into registers (own |p|^2 folded in at combine).
    float m2x[Q], m2y[Q], m2z[Q], acc[Q];
    #pragma unroll
    for (int q = 0; q < Q; ++q) {
        const float* p = pts + 3 * (base + qt * QTILE + q * BLOCK + threadIdx.x);
        m2x[q] = -2.0f * p[0];
        m2y[q] = -2.0f * p[1];
        m2z[q] = -2.0f * p[2];
        acc[q] = 1e30f;
    }
    __syncthreads();

    #pragma unroll 2
    for (int k = 0; k < KTILE; k += 2) {
        float4 o0 = buf[k + 0];   // wave-uniform index: broadcast, conflict-free
        float4 o1 = buf[k + 1];
        #pragma unroll
        for (int q = 0; q < Q; ++q) {
            float t0 = fmaf(m2z[q], o0.z, fmaf(m2y[q], o0.y, fmaf(m2x[q], o0.x, o0.w)));
            float t1 = fmaf(m2z[q], o1.z, fmaf(m2y[q], o1.y, fmaf(m2x[q], o1.x, o1.w)));
            acc[q] = fminf(acc[q], fminf(t0, t1));
        }
    }

    float* pp = partial + (size_t)((dir * N_BATCH + batch) * KSPLIT + ks) * N_PTS
                + qt * QTILE + threadIdx.x;
    #pragma unroll
    for (int q = 0; q < Q; ++q)
        pp[q * BLOCK] = acc[q];   // coalesced per q
}

// Combine KSPLIT partials per query, add |p|^2, clamp, sqrt, scale, reduce.
__global__ __launch_bounds__(BLOCK) void chamfer_combine(
    const float* __restrict__ tpl, const float* __restrict__ src,
    const float* __restrict__ partial, float* __restrict__ out) {
    int idx   = blockIdx.x * BLOCK + threadIdx.x;  // 0 .. 131071
    int dir   = idx >> 16;
    int batch = (idx >> 12) & (N_BATCH - 1);
    int q     = idx & (N_PTS - 1);

    const float* pts = (dir == 0) ? src : tpl;
    const float* p = pts + 3 * ((batch << 12) + q);
    float x = p[0], y = p[1], z = p[2];
    float pw = fmaf(x, x, fmaf(y, y, z * z));

    const float* pp = partial + (size_t)((dir * N_BATCH + batch) * KSPLIT) * N_PTS + q;
    float d = 1e30f;
    #pragma unroll
    for (int ks = 0; ks < KSPLIT; ++ks)
        d = fminf(d, pp[ks * N_PTS]);   // coalesced across threads

    d = fmaxf(d + pw, 0.0f);            // matches jnp.maximum(..., 0)
    float val = sqrtf(d) * INV_CNT;

    #pragma unroll
    for (int off = 32; off > 0; off >>= 1)
        val += __shfl_down(val, off);
    if ((threadIdx.x & 63) == 0)
        atomicAdd(out, val);
}

extern "C" void kernel_launch(void* const* d_in, const int* in_sizes, int n_in,
                              void* d_out, int out_size, void* d_ws, size_t ws_size,
                              hipStream_t stream) {
    const float* tpl = (const float*)d_in[0];
    const float* src = (const float*)d_in[1];
    float* out = (float*)d_out;
    float* partial = (float*)d_ws;  // 2*16*8*4096 floats = 4 MB

    dim3 gridP(QT_PER * KSPLIT, N_BATCH, 2);  // (16, 16, 2) = 512 blocks
    hipLaunchKernelGGL(chamfer_partial, gridP, dim3(BLOCK), 0, stream,
                       tpl, src, partial, out);
    hipLaunchKernelGGL(chamfer_combine, dim3((2 * N_BATCH * N_PTS) / BLOCK),
                       dim3(BLOCK), 0, stream, tpl, src, partial, out);
}

// Round 3
// 100.801 us; speedup vs baseline: 1.4226x; 1.2581x over previous
//
#include <hip/hip_runtime.h>

#define N_PTS   4096
#define N_BATCH 16
#define BLOCK   256
#define Q       4                 // query points per thread (register tile)
#define QTILE   (BLOCK * Q)       // 1024
#define KTILE   512               // opposite points staged in LDS (8 KB)
#define KSPLIT  (N_PTS / KTILE)   // 8
#define QT_PER  (N_PTS / QTILE)   // 4
#define INV_CNT (1.0f / (2.0f * N_BATCH * N_PTS))

// Partial mins: block handles QTILE queries x KTILE opposite points.
// Each LDS value is reused Q=4x from registers; 3.5 VALU instr/pair
// (3 fma + chained v_min3 every 2 pairs).
__global__ __launch_bounds__(BLOCK, 4) void chamfer_partial(
    const float* __restrict__ tpl, const float* __restrict__ src,
    float* __restrict__ partial, float* __restrict__ out) {
    __shared__ float4 buf[KTILE];

    const int qt    = blockIdx.x & (QT_PER - 1);
    const int ks    = blockIdx.x >> 2;            // QT_PER == 4
    const int batch = blockIdx.y;
    const int dir   = blockIdx.z;
    const float* pts = (dir == 0) ? src : tpl;    // dist1: per source point
    const float* oth = (dir == 0) ? tpl : src;
    const int base = batch * N_PTS;

    if (blockIdx.x == 0 && batch == 0 && dir == 0 && threadIdx.x == 0)
        out[0] = 0.0f;   // combine's atomics run strictly after (stream order)

    // Stage + pack opposite tile: (x,y,z) -> (x,y,z,|o|^2)
    #pragma unroll
    for (int r = 0; r < KTILE / BLOCK; ++r) {
        int i = threadIdx.x + BLOCK * r;
        const float* o = oth + 3 * (base + ks * KTILE + i);
        float x = o[0], y = o[1], z = o[2];
        buf[i] = make_float4(x, y, z, fmaf(x, x, fmaf(y, y, z * z)));
    }

    // Q query points in registers (own |p|^2 folded in at combine).
    float m2x[Q], m2y[Q], m2z[Q], acc[Q];
    #pragma unroll
    for (int q = 0; q < Q; ++q) {
        const float* p = pts + 3 * (base + qt * QTILE + q * BLOCK + threadIdx.x);
        m2x[q] = -2.0f * p[0];
        m2y[q] = -2.0f * p[1];
        m2z[q] = -2.0f * p[2];
        acc[q] = 1e30f;
    }
    __syncthreads();

    #pragma unroll 2
    for (int k = 0; k < KTILE; k += 4) {
        // Wave-uniform index: LDS broadcast, conflict-free.
        float4 o0 = buf[k + 0];
        float4 o1 = buf[k + 1];
        float4 o2 = buf[k + 2];
        float4 o3 = buf[k + 3];
        #pragma unroll
        for (int q = 0; q < Q; ++q) {
            float t0 = fmaf(m2z[q], o0.z, fmaf(m2y[q], o0.y, fmaf(m2x[q], o0.x, o0.w)));
            float t1 = fmaf(m2z[q], o1.z, fmaf(m2y[q], o1.y, fmaf(m2x[q], o1.x, o1.w)));
            float t2 = fmaf(m2z[q], o2.z, fmaf(m2y[q], o2.y, fmaf(m2x[q], o2.x, o2.w)));
            float t3 = fmaf(m2z[q], o3.z, fmaf(m2y[q], o3.y, fmaf(m2x[q], o3.x, o3.w)));
            acc[q] = fminf(acc[q], fminf(t0, t1));  // -> v_min3_f32
            acc[q] = fminf(acc[q], fminf(t2, t3));  // -> v_min3_f32
        }
    }

    float* pp = partial + (size_t)((dir * N_BATCH + batch) * KSPLIT + ks) * N_PTS
                + qt * QTILE + threadIdx.x;
    #pragma unroll
    for (int q = 0; q < Q; ++q)
        pp[q * BLOCK] = acc[q];   // coalesced per q
}

// Combine KSPLIT partials per query, add |p|^2, clamp, sqrt, scale, reduce.
// 128 blocks x 4 queries/thread; one atomic per block.
#define CBLOCKS 128
#define CQ      4
__global__ __launch_bounds__(BLOCK) void chamfer_combine(
    const float* __restrict__ tpl, const float* __restrict__ src,
    const float* __restrict__ partial, float* __restrict__ out) {
    __shared__ float wsum[BLOCK / 64];

    float val = 0.0f;
    #pragma unroll
    for (int j = 0; j < CQ; ++j) {
        int idx   = blockIdx.x * (BLOCK * CQ) + j * BLOCK + threadIdx.x;
        int dir   = idx >> 16;
        int batch = (idx >> 12) & (N_BATCH - 1);
        int q     = idx & (N_PTS - 1);

        const float* pts = (dir == 0) ? src : tpl;
        const float* p = pts + 3 * ((batch << 12) + q);
        float x = p[0], y = p[1], z = p[2];
        float pw = fmaf(x, x, fmaf(y, y, z * z));

        const float* pp = partial + (size_t)((dir * N_BATCH + batch) * KSPLIT) * N_PTS + q;
        float d = 1e30f;
        #pragma unroll
        for (int ks = 0; ks < KSPLIT; ++ks)
            d = fminf(d, pp[ks * N_PTS]);   // coalesced across threads

        d = fmaxf(d + pw, 0.0f);            // matches jnp.maximum(..., 0)
        val += sqrtf(d) * INV_CNT;
    }

    // Wave64 reduction, then cross-wave via LDS, one atomic per block.
    #pragma unroll
    for (int off = 32; off > 0; off >>= 1)
        val += __shfl_down(val, off);
    if ((threadIdx.x & 63) == 0)
        wsum[threadIdx.x >> 6] = val;
    __syncthreads();
    if (threadIdx.x == 0) {
        float s = wsum[0] + wsum[1] + wsum[2] + wsum[3];
        atomicAdd(out, s);
    }
}

extern "C" void kernel_launch(void* const* d_in, const int* in_sizes, int n_in,
                              void* d_out, int out_size, void* d_ws, size_t ws_size,
                              hipStream_t stream) {
    const float* tpl = (const float*)d_in[0];
    const float* src = (const float*)d_in[1];
    float* out = (float*)d_out;
    float* partial = (float*)d_ws;  // 2*16*8*4096 floats = 4 MB

    dim3 gridP(QT_PER * KSPLIT, N_BATCH, 2);  // (32, 16, 2) = 1024 blocks
    hipLaunchKernelGGL(chamfer_partial, gridP, dim3(BLOCK), 0, stream,
                       tpl, src, partial, out);
    hipLaunchKernelGGL(chamfer_combine, dim3(CBLOCKS), dim3(BLOCK), 0, stream,
                       tpl, src, partial, out);
}